// Round 13
// baseline (142.366 us; speedup 1.0000x reference)
//
#include <hip/hip_runtime.h>

// MoE top-2 of 3x3 SAME convs via bf16 MFMA implicit GEMM.
//
// R19: ZERO in-loop barriers = R12's one-shot A-stage (72KB, verified
// layout) + R14/R18's mechanical asm B-pipeline, now 3-deep.
// R18 post-mortem: main ~38us (below top-5 cutoff), occupancy play paid
// (-5us). Residual cost ~6k cy/group vs 240cy MFMA: either (a) 6x
// per-group vmcnt(0)+s_barrier collective stalls, or (b) raw L2/L3
// latency at 8-12 waves/CU. R19 isolates (a):
//  - Stage ALL A once: 72 chunks x 1KB (e2 x rs9 x ks2 x mtl2), 18 gll per
//    wave, ONE barrier total. R12's exact decode/layout (passed, correct).
//  - 6 groups g=(s,ks), NO barriers: B via volatile-asm global_load_dwordx4
//    into bfb[3][6] (triple buffer, prefetch distance 2 groups); one
//    counted s_waitcnt vmcnt(12) per group (tail: 6,0). Ledger: prologue
//    A18+B0:6+B1:6=30 -> wait(12)=A done; per g: issue B(g+2) ->18 ->
//    wait(12) completes exactly B(g).
//  - sched_barrier(0) after each wait (rule #18), setprio(1) on MFMA.
//  - LDS 73728 -> 2 blocks/CU (8 waves), but waves slide independently.
// Predicted: VGPR ~100-115 (+64 AGPR), Mfma ->35-45%, main 38->26-31us,
// total ->129-134us. Flat main => both mechanisms dead => floor call.

#define BB 64
#define CC 64
#define COO 64
#define HH 56
#define WW 56

typedef __bf16 bf16x8 __attribute__((ext_vector_type(8)));
typedef float  f32x4  __attribute__((ext_vector_type(4)));

// ---- prep: thin-block transpose (1 barrier) + weight pack (R17 verbatim) ---
__global__ __launch_bounds__(256) void prep_kernel(
    const float* __restrict__ x, const float* __restrict__ Wexp,
    __bf16* __restrict__ xT, __bf16* __restrict__ Wpack)
{
    const int bx  = blockIdx.x;
    const int tid = threadIdx.x;

    if (bx < 3712) {
        // ---- xpose: block = one padded row (b, hp) -------------------------
        // Output row layout: [cg 8][wc 66][8 c] (c-octet-major), 4224 bf16.
        const int b  = bx / 58;
        const int hp = bx - b * 58;
        __bf16* dst = xT + ((size_t)b * 58 + hp) * 4224;

        if (hp == 0 || hp == 57) {           // pad row: zero-fill, no LDS
            bf16x8 z = {};
            for (int j = tid; j < 528; j += 256)
                *(bf16x8*)(dst + j * 8) = z;
            return;
        }

        __shared__ __align__(16) float tile[CC * WW];   // [c][w] linear, 14.3KB
        const int h = hp - 1;
        const float* xb = x + ((size_t)b * CC * HH + h) * WW;  // + c*HH*WW

        // 896 16B chunks: chunk i = c*14 + wq -> tile[i*4 .. i*4+3].
        for (int i = tid; i < 896; i += 256) {
            const int c = i / 14, wq = i - c * 14;
            const f32x4 f = *(const f32x4*)(xb + (size_t)c * (HH * WW) + wq * 4);
            *(f32x4*)&tile[i * 4] = f;
        }
        __syncthreads();                     // the ONLY barrier

        // Transpose-write: j = cg*66 + wc; 16B coalesced stores.
        for (int j = tid; j < 528; j += 256) {
            const int cg = j / 66, wc = j - cg * 66;
            bf16x8 v = {};
            if (wc >= 1 && wc <= WW) {
                #pragma unroll
                for (int u = 0; u < 8; ++u)
                    v[u] = (__bf16)tile[(cg * 8 + u) * WW + (wc - 1)];
            }
            *(bf16x8*)(dst + j * 8) = v;
        }
    } else {
        // ---- wpack part (verified R3+ body) --------------------------------
        // Wpack[e*36864 + rs*4096 + ks*2048 + mt*512 + lane*8 + j]
        //   = bf16( Wexp[e][mt*16+(lane&15)][ks*32+(lane>>4)*8+j][r][s] )
        const int wp = bx - 3712;            // 0..71
        const int e  = wp / 9, rs = wp - e * 9;
        const int r  = rs / 3, s  = rs - r * 3;
        for (int idx = tid; idx < 4096; idx += 256) {
            const int ks   = idx >> 11;
            const int rem  = idx & 2047;
            const int mt   = rem >> 9;
            const int lane = (rem >> 3) & 63;
            const int j    = idx & 7;
            const int co = mt * 16 + (lane & 15);
            const int c  = ks * 32 + ((lane >> 4) << 3) + j;
            const float v = Wexp[((((size_t)e * COO + co) * CC + c) * 3 + r) * 3 + s];
            Wpack[(size_t)e * 36864 + (size_t)rs * 4096 + idx] = (__bf16)v;
        }
    }
}

// ---- Main: one-shot A stage, barrier-free counted B pipeline ---------------
__global__ __launch_bounds__(256, 2) void moe_conv_mfma(
    const __bf16* __restrict__ xT, const __bf16* __restrict__ Wpack,
    const float* __restrict__ gate_w, const int* __restrict__ gate_i,
    const float* __restrict__ bexp, float* __restrict__ out)
{
    // All A-frags: chunk q = rs*8 + slot*4 + ks*2 + mtl (R12 layout),
    // ldsA[q*512 + lane*8 + j]. 72 chunks x 1KB = 73,728 B.
    __shared__ __align__(16) __bf16 ldsA[72 * 512];

    // XCD swizzle: 1792 blocks, 224 consecutive swz per XCD.
    const int bid = blockIdx.x;
    const int swz = (bid & 7) * 224 + (bid >> 3);
    const int b   = swz / 28;
    const int rem = swz - b * 28;
    const int h0  = (rem >> 1) * 4;     // output rows h0..h0+3
    const int mh  = rem & 1;            // CO half: mt = mh*2 + mtl

    const int tid = threadIdx.x;
    const int wid = tid >> 6, lane = tid & 63;
    const int n15 = lane & 15, quad = lane >> 4;
    const int wcol = wid * 16 + n15;    // padded col 0..63

    const int   e0 = gate_i[b * 2 + 0], e1 = gate_i[b * 2 + 1];
    const float g0 = gate_w[b * 2 + 0], g1 = gate_w[b * 2 + 1];
    const __bf16* w0 = Wpack + (size_t)e0 * 36864;
    const __bf16* w1 = Wpack + (size_t)e1 * 36864;

    // One-shot A stage: wave wid loads chunks q = wid*18 .. wid*18+17
    // (R12's verified decode); dest = uniform base + lane*16B.
    #pragma unroll
    for (int i = 0; i < 18; ++i) {
        const int q    = wid * 18 + i;
        const int rs   = q >> 3;
        const int rm   = q & 7;
        const int slot = rm >> 2, ks = (rm >> 1) & 1, mtl = rm & 1;
        const __bf16* src = (slot ? w1 : w0) + (size_t)rs * 4096
                          + ks * 2048 + (mh * 2 + mtl) * 512 + lane * 8;
        __bf16* dstp = &ldsA[q * 512 + lane * 8];
        __builtin_amdgcn_global_load_lds(
            (const __attribute__((address_space(1))) unsigned int*)src,
            (__attribute__((address_space(3))) unsigned int*)dstp, 16, 0, 0);
    }

    // xT strides (bf16): b 244992, hp 4224, cg 528 (cg = ks*4 + quad).
    const __bf16* pqh = xT + (size_t)b * 244992 + (size_t)h0 * 4224
                      + quad * 528 + wcol * 8;

    f32x4 acc[2][2][4] = {};            // [slot][mtl][t] -> AGPRs (64)
    f32x4 bfb[3][6];                    // 3-deep B pipeline: [buf][row 0..5]

    // Issue the 6 deduped B-row loads for group m=(s=m>>1, ks=m&1) into
    // bfb[m%3]: volatile asm = unmovable, results forcibly live.
    auto issueB = [&](int m) {
        const int s = m >> 1, ks = m & 1, mb = m % 3;
        #pragma unroll
        for (int t = 0; t < 6; ++t) {
            const __bf16* a = pqh + (size_t)t * 4224 + s * 8 + ks * 2112;
            asm volatile("global_load_dwordx4 %0, %1, off"
                         : "=&v"(bfb[mb][t]) : "v"(a));
        }
    };

    // Prologue: A(18) + B0(6) + B1(6) = 30 outstanding.
    issueB(0);
    issueB(1);
    asm volatile("s_waitcnt vmcnt(12)" ::: "memory");  // A landed; B0,B1 fly
    __builtin_amdgcn_sched_barrier(0);
    __builtin_amdgcn_s_barrier();       // the ONLY barrier in this kernel
    __builtin_amdgcn_sched_barrier(0);

    // 6 groups, zero barriers. Per g: issue B(g+2) -> 18 out -> wait
    // vmcnt(12) completes exactly B(g) -> 48-MFMA cluster.
    #pragma unroll
    for (int g = 0; g < 6; ++g) {
        const int s = g >> 1, ks = g & 1, buf = g % 3;
        if (g <= 3) {
            issueB(g + 2);
            asm volatile("s_waitcnt vmcnt(12)" ::: "memory");
        } else if (g == 4) {
            asm volatile("s_waitcnt vmcnt(6)" ::: "memory");
        } else {
            asm volatile("s_waitcnt vmcnt(0)" ::: "memory");
        }
        __builtin_amdgcn_sched_barrier(0);  // rule #18: pin MFMAs below wait

        __builtin_amdgcn_s_setprio(1);
        #pragma unroll
        for (int r = 0; r < 3; ++r) {
            #pragma unroll
            for (int slot = 0; slot < 2; ++slot) {
                #pragma unroll
                for (int mtl = 0; mtl < 2; ++mtl) {
                    const bf16x8 af = *(const bf16x8*)
                        &ldsA[(((r * 3 + s) * 8) + slot * 4 + ks * 2 + mtl) * 512
                              + lane * 8];
                    #pragma unroll
                    for (int t = 0; t < 4; ++t)
                        acc[slot][mtl][t] = __builtin_amdgcn_mfma_f32_16x16x32_bf16(
                            af, __builtin_bit_cast(bf16x8, bfb[buf][r + t]),
                            acc[slot][mtl][t], 0, 0, 0);
                }
            }
        }
        __builtin_amdgcn_s_setprio(0);
    }

    // Epilogue: D layout col=lane&15 (pixel), row=quad*4+reg (co within mt).
    if (wcol < WW) {
        #pragma unroll
        for (int t = 0; t < 4; ++t) {
            const int h = h0 + t;
            #pragma unroll
            for (int mtl = 0; mtl < 2; ++mtl) {
                #pragma unroll
                for (int v = 0; v < 4; ++v) {
                    const int co = (mh * 2 + mtl) * 16 + quad * 4 + v;
                    float a0 = acc[0][mtl][t][v] + bexp[e0 * COO + co];
                    float a1 = acc[1][mtl][t][v] + bexp[e1 * COO + co];
                    a0 = fmaxf(a0, 0.f);
                    a1 = fmaxf(a1, 0.f);
                    out[(((size_t)b * COO + co) * HH + h) * WW + wcol] =
                        g0 * a0 + g1 * a1;
                }
            }
        }
    }
}

extern "C" void kernel_launch(void* const* d_in, const int* in_sizes, int n_in,
                              void* d_out, int out_size, void* d_ws, size_t ws_size,
                              hipStream_t stream) {
    const float* x      = (const float*)d_in[0];
    const float* gate_w = (const float*)d_in[1];
    const int*   gate_i = (const int*)  d_in[2];
    const float* Wexp   = (const float*)d_in[3];
    const float* bexp   = (const float*)d_in[4];
    float* out = (float*)d_out;

    // Wpack first (fixed 589,824 B, 16B-aligned), then xT (31,358,976 B).
    __bf16* Wpack = (__bf16*)d_ws;
    __bf16* xT    = (__bf16*)((char*)d_ws + 589824);

    prep_kernel<<<dim3(3784), 256, 0, stream>>>(x, Wexp, xT, Wpack);
    moe_conv_mfma<<<dim3(1792), 256, 0, stream>>>(xT, Wpack, gate_w, gate_i,
                                                  bexp, out);
}

// Round 14
// 141.976 us; speedup vs baseline: 1.0027x; 1.0027x over previous
//
#include <hip/hip_runtime.h>

// MoE top-2 of 3x3 SAME convs via bf16 MFMA implicit GEMM.
//
// R20: max-TLP operating point. R19 (barrier-free, 3-deep counted pipeline)
// was NULL vs R18 => collective barriers exonerated; only occupancy has
// ever moved main (59->47->43->38 each tracked +blocks/CU). Push it:
//  - CO quartered (mq): acc 32 f32 (AGPRs), grid 3584 (14/CU; bijective
//    XCD swizzle, 448/XCD).
//  - A staged ONCE: 36 chunks x 1KB = 36KB LDS (e2 x rs9 x ks2 x mt1),
//    9 gll/wave (uniform ledger), ONE barrier total.
//  - 6 groups, zero barriers: B dbuf via volatile asm, issueB(g+1) at top
//    of g (full-group cover), uniform s_waitcnt vmcnt(6)/group, vmcnt(0)
//    tail only. Ledger: prologue A9+B0=15, wait(6)=A done; per g: +6 -> 12,
//    wait(6) completes exactly B(g).
//  - launch_bounds(256,4): target 4 blocks/CU = 16 waves (2x R18).
//    B-traffic x2 vs R18: proven non-binding (R15).
// Predicted: VGPR ~95-110 (+32 AGPR), Occ ->25-35%, main 38->28-33us,
// total ->130-136us. Flat => TLP theory dead => floor call next.

#define BB 64
#define CC 64
#define COO 64
#define HH 56
#define WW 56

typedef __bf16 bf16x8 __attribute__((ext_vector_type(8)));
typedef float  f32x4  __attribute__((ext_vector_type(4)));

// ---- prep: thin-block transpose (1 barrier) + weight pack (R17 verbatim) ---
__global__ __launch_bounds__(256) void prep_kernel(
    const float* __restrict__ x, const float* __restrict__ Wexp,
    __bf16* __restrict__ xT, __bf16* __restrict__ Wpack)
{
    const int bx  = blockIdx.x;
    const int tid = threadIdx.x;

    if (bx < 3712) {
        // ---- xpose: block = one padded row (b, hp) -------------------------
        // Output row layout: [cg 8][wc 66][8 c] (c-octet-major), 4224 bf16.
        const int b  = bx / 58;
        const int hp = bx - b * 58;
        __bf16* dst = xT + ((size_t)b * 58 + hp) * 4224;

        if (hp == 0 || hp == 57) {           // pad row: zero-fill, no LDS
            bf16x8 z = {};
            for (int j = tid; j < 528; j += 256)
                *(bf16x8*)(dst + j * 8) = z;
            return;
        }

        __shared__ __align__(16) float tile[CC * WW];   // [c][w] linear, 14.3KB
        const int h = hp - 1;
        const float* xb = x + ((size_t)b * CC * HH + h) * WW;  // + c*HH*WW

        // 896 16B chunks: chunk i = c*14 + wq -> tile[i*4 .. i*4+3].
        for (int i = tid; i < 896; i += 256) {
            const int c = i / 14, wq = i - c * 14;
            const f32x4 f = *(const f32x4*)(xb + (size_t)c * (HH * WW) + wq * 4);
            *(f32x4*)&tile[i * 4] = f;
        }
        __syncthreads();                     // the ONLY barrier

        // Transpose-write: j = cg*66 + wc; 16B coalesced stores.
        for (int j = tid; j < 528; j += 256) {
            const int cg = j / 66, wc = j - cg * 66;
            bf16x8 v = {};
            if (wc >= 1 && wc <= WW) {
                #pragma unroll
                for (int u = 0; u < 8; ++u)
                    v[u] = (__bf16)tile[(cg * 8 + u) * WW + (wc - 1)];
            }
            *(bf16x8*)(dst + j * 8) = v;
        }
    } else {
        // ---- wpack part (verified R3+ body) --------------------------------
        // Wpack[e*36864 + rs*4096 + ks*2048 + mt*512 + lane*8 + j]
        //   = bf16( Wexp[e][mt*16+(lane&15)][ks*32+(lane>>4)*8+j][r][s] )
        const int wp = bx - 3712;            // 0..71
        const int e  = wp / 9, rs = wp - e * 9;
        const int r  = rs / 3, s  = rs - r * 3;
        for (int idx = tid; idx < 4096; idx += 256) {
            const int ks   = idx >> 11;
            const int rem  = idx & 2047;
            const int mt   = rem >> 9;
            const int lane = (rem >> 3) & 63;
            const int j    = idx & 7;
            const int co = mt * 16 + (lane & 15);
            const int c  = ks * 32 + ((lane >> 4) << 3) + j;
            const float v = Wexp[((((size_t)e * COO + co) * CC + c) * 3 + r) * 3 + s];
            Wpack[(size_t)e * 36864 + (size_t)rs * 4096 + idx] = (__bf16)v;
        }
    }
}

// ---- Main: quarter-CO blocks, one-shot A, barrier-free counted B dbuf ------
__global__ __launch_bounds__(256, 4) void moe_conv_mfma(
    const __bf16* __restrict__ xT, const __bf16* __restrict__ Wpack,
    const float* __restrict__ gate_w, const int* __restrict__ gate_i,
    const float* __restrict__ bexp, float* __restrict__ out)
{
    // All A-frags: chunk q = rs*4 + slot*2 + ks, ldsA[q*512 + lane*8 + j].
    // 36 chunks x 1KB = 36,864 B.
    __shared__ __align__(16) __bf16 ldsA[36 * 512];

    // XCD swizzle: 3584 blocks, 448 consecutive swz per XCD.
    const int bid = blockIdx.x;
    const int swz = (bid & 7) * 448 + (bid >> 3);
    const int b   = swz / 56;
    const int rem = swz - b * 56;
    const int h0  = (rem >> 2) * 4;     // output rows h0..h0+3
    const int mq  = rem & 3;            // CO quarter: mt = mq

    const int tid = threadIdx.x;
    const int wid = tid >> 6, lane = tid & 63;
    const int n15 = lane & 15, quad = lane >> 4;
    const int wcol = wid * 16 + n15;    // padded col 0..63

    const int   e0 = gate_i[b * 2 + 0], e1 = gate_i[b * 2 + 1];
    const float g0 = gate_w[b * 2 + 0], g1 = gate_w[b * 2 + 1];
    const __bf16* w0 = Wpack + (size_t)e0 * 36864;
    const __bf16* w1 = Wpack + (size_t)e1 * 36864;

    // One-shot A stage: wave wid loads chunks q = wid*9 .. wid*9+8.
    // q -> rs = q>>2, slot = (q>>1)&1, ks = q&1; dest = uniform + lane*16B.
    #pragma unroll
    for (int i = 0; i < 9; ++i) {
        const int q    = wid * 9 + i;
        const int rs   = q >> 2;
        const int slot = (q >> 1) & 1, ks = q & 1;
        const __bf16* src = (slot ? w1 : w0) + (size_t)rs * 4096
                          + ks * 2048 + mq * 512 + lane * 8;
        __bf16* dstp = &ldsA[q * 512 + lane * 8];
        __builtin_amdgcn_global_load_lds(
            (const __attribute__((address_space(1))) unsigned int*)src,
            (__attribute__((address_space(3))) unsigned int*)dstp, 16, 0, 0);
    }

    // xT strides (bf16): b 244992, hp 4224, cg 528 (cg = ks*4 + quad).
    const __bf16* pqh = xT + (size_t)b * 244992 + (size_t)h0 * 4224
                      + quad * 528 + wcol * 8;

    f32x4 acc[2][4] = {};               // [slot][t] -> 32 AGPRs
    f32x4 bfb[2][6];                    // B dbuf: [buf][row 0..5] = 48 VGPRs

    // Issue the 6 deduped B-row loads for group m=(s=m>>1, ks=m&1) into
    // bfb[m&1]: volatile asm = unmovable, results forcibly live.
    auto issueB = [&](int m) {
        const int s = m >> 1, ks = m & 1, mb = m & 1;
        #pragma unroll
        for (int t = 0; t < 6; ++t) {
            const __bf16* a = pqh + (size_t)t * 4224 + s * 8 + ks * 2112;
            asm volatile("global_load_dwordx4 %0, %1, off"
                         : "=&v"(bfb[mb][t]) : "v"(a));
        }
    };

    // Prologue: A(9) + B0(6) = 15 outstanding; wait(6) completes exactly A.
    issueB(0);
    asm volatile("s_waitcnt vmcnt(6)" ::: "memory");
    __builtin_amdgcn_sched_barrier(0);
    __builtin_amdgcn_s_barrier();       // the ONLY barrier (B0 stays in flight)
    __builtin_amdgcn_sched_barrier(0);

    // 6 groups, zero barriers. Top of g: issue B(g+1) into buf^1 (last read
    // in g-1, done) -> 12 outstanding; wait(6) completes exactly B(g),
    // which was issued a full group earlier.
    #pragma unroll
    for (int g = 0; g < 6; ++g) {
        const int s = g >> 1, ks = g & 1, buf = g & 1;
        if (g < 5) {
            issueB(g + 1);
            asm volatile("s_waitcnt vmcnt(6)" ::: "memory");
        } else {
            asm volatile("s_waitcnt vmcnt(0)" ::: "memory");
        }
        __builtin_amdgcn_sched_barrier(0);  // rule #18: pin MFMAs below wait

        __builtin_amdgcn_s_setprio(1);
        #pragma unroll
        for (int r = 0; r < 3; ++r) {
            #pragma unroll
            for (int slot = 0; slot < 2; ++slot) {
                const bf16x8 af = *(const bf16x8*)
                    &ldsA[((r * 3 + s) * 4 + slot * 2 + ks) * 512 + lane * 8];
                #pragma unroll
                for (int t = 0; t < 4; ++t)
                    acc[slot][t] = __builtin_amdgcn_mfma_f32_16x16x32_bf16(
                        af, __builtin_bit_cast(bf16x8, bfb[buf][r + t]),
                        acc[slot][t], 0, 0, 0);
            }
        }
        __builtin_amdgcn_s_setprio(0);
    }

    // Epilogue: D layout col=lane&15 (pixel), row=quad*4+reg (co within mt).
    if (wcol < WW) {
        #pragma unroll
        for (int t = 0; t < 4; ++t) {
            const int h = h0 + t;
            #pragma unroll
            for (int v = 0; v < 4; ++v) {
                const int co = mq * 16 + quad * 4 + v;
                float a0 = acc[0][t][v] + bexp[e0 * COO + co];
                float a1 = acc[1][t][v] + bexp[e1 * COO + co];
                a0 = fmaxf(a0, 0.f);
                a1 = fmaxf(a1, 0.f);
                out[(((size_t)b * COO + co) * HH + h) * WW + wcol] =
                    g0 * a0 + g1 * a1;
            }
        }
    }
}

extern "C" void kernel_launch(void* const* d_in, const int* in_sizes, int n_in,
                              void* d_out, int out_size, void* d_ws, size_t ws_size,
                              hipStream_t stream) {
    const float* x      = (const float*)d_in[0];
    const float* gate_w = (const float*)d_in[1];
    const int*   gate_i = (const int*)  d_in[2];
    const float* Wexp   = (const float*)d_in[3];
    const float* bexp   = (const float*)d_in[4];
    float* out = (float*)d_out;

    // Wpack first (fixed 589,824 B, 16B-aligned), then xT (31,358,976 B).
    __bf16* Wpack = (__bf16*)d_ws;
    __bf16* xT    = (__bf16*)((char*)d_ws + 589824);

    prep_kernel<<<dim3(3784), 256, 0, stream>>>(x, Wexp, xT, Wpack);
    moe_conv_mfma<<<dim3(3584), 256, 0, stream>>>(xT, Wpack, gate_w, gate_i,
                                                  bexp, out);
}